// Round 8
// baseline (213.599 us; speedup 1.0000x reference)
//
#include <hip/hip_runtime.h>
#include <math.h>

// Problem constants (reference: B=2, S=T=400, D=512)
#define BB 2
#define SS 400
#define DD 512
#define TWO_LOG2E 2.8853900817779268f   // tanh(x) = 1 - 2/(exp2(TWO_LOG2E*x)+1)

#if __has_builtin(__builtin_amdgcn_exp2f)
#define EXP2F(x) __builtin_amdgcn_exp2f(x)
#else
#define EXP2F(x) exp2f(x)
#endif
#define RCPF(x) __builtin_amdgcn_rcpf(x)

// Workspace float layout (10.0 MB total — unchanged from R6/R7):
//   Ea   [0,       409600) : exp2(2L*(input@Wq + bq))            [B,T,D]
//   M    [409600,  819200) : mb@Wout_top                         [B,S,D]
//   Eb4  [819200, 1228800) : exp2(2L*(mb@Wc)), packed [B][D/4][S][4]
//   part [1228800,2508800) : partial scores, [eq][B][T][S] (4x320000)
// score(t,s) = const(t-indep) - 2*sum_e v_e/(Ea*Eb+1); const drops in softmax.
// out0 gets input@Wout_bot + bout from k1 (m==3); k3 adds align@M in-place.
#define EAOFF 0
#define MOFF 409600
#define EB4OFF 819200
#define PARTOFF 1228800
#define PARTCH 320000

// ---------------------------------------------------------------------------
// K1: four GEMMs (800x512x512), hybrid scalar-A / LDS-B.
// Grid (25 rowgroups, 8 colgroups, 4 gemms) = 800 blocks, 256 thr.
// Block tile 32 rows x 64 cols; wave = 8 rows (uniform base -> A via
// s_load_dwordx4), lane = 1 col (Bs[k][lane] ds_read_b32, conflict-free).
// 8 acc/thread -> 3200 waves = 3.1/SIMD; A costs no vector resources, so
// full TLP and full FMA density simultaneously. Bs double-buffered (16 KB).
// Fused epilogues: m0 Ea=exp2(2L(acc+bq)); m1 Eb4 transposed-packed
// exp2(2L acc); m2 M; m3 out0=acc+bout in [T,B,D].
// ---------------------------------------------------------------------------
__global__ __launch_bounds__(256) void k1_gemm(
    const float* __restrict__ input, const float* __restrict__ mb,
    const float* __restrict__ Wq, const float* __restrict__ bq,
    const float* __restrict__ Wc, const float* __restrict__ Wout,
    const float* __restrict__ bout, float* __restrict__ ws,
    float* __restrict__ out0)
{
    const int lane = threadIdx.x & 63;
    const int w    = threadIdx.x >> 6;           // wave 0..3
    const int r0   = blockIdx.x * 32;
    const int c0   = blockIdx.y * 64;
    const int m    = blockIdx.z;
    const int c    = c0 + lane;

    const float* __restrict__ A = (m == 0 || m == 3) ? input : mb;
    const float* __restrict__ W =
        (m == 0) ? Wq : (m == 1) ? Wc : (m == 2) ? Wout : Wout + DD * DD;

    // wave-uniform row base -> scalar A loads
    const int rw = __builtin_amdgcn_readfirstlane(r0 + w * 8);
    const float* __restrict__ Ar = A + (size_t)rw * DD;

    __shared__ float Bs[2][32][64];

    const int f0 = threadIdx.x;                  // float4 slot, pass 0
    float4 st[2];
    auto GLOAD = [&](int k0) {
        #pragma unroll
        for (int p = 0; p < 2; ++p) {
            const int f = f0 + p * 256;          // 0..511 over [32][16]
            st[p] = *(const float4*)(W + (size_t)(k0 + (f >> 4)) * DD
                                       + c0 + (f & 15) * 4);
        }
    };
    auto SSTORE = [&](int buf) {
        #pragma unroll
        for (int p = 0; p < 2; ++p) {
            const int f = f0 + p * 256;
            *(float4*)&Bs[buf][f >> 4][(f & 15) * 4] = st[p];
        }
    };

    float acc[8];
    #pragma unroll
    for (int r = 0; r < 8; ++r) acc[r] = 0.f;

    GLOAD(0);
    SSTORE(0);
    __syncthreads();

    for (int t = 0; t < 16; ++t) {
        const int buf = t & 1;
        if (t < 15) GLOAD((t + 1) * 32);
        const int kb = t * 32;
        #pragma unroll
        for (int kk = 0; kk < 32; kk += 4) {
            float4 a[8];                          // wave-uniform -> SGPRs
            #pragma unroll
            for (int r = 0; r < 8; ++r)
                a[r] = *(const float4*)(Ar + (size_t)r * DD + kb + kk);
            float b[4];
            #pragma unroll
            for (int j = 0; j < 4; ++j) b[j] = Bs[buf][kk + j][lane];
            #pragma unroll
            for (int j = 0; j < 4; ++j) {
                #pragma unroll
                for (int r = 0; r < 8; ++r)
                    acc[r] = fmaf((&a[r].x)[j], b[j], acc[r]);
            }
        }
        if (t < 15) {
            __syncthreads();      // all waves done reading buf^1 (tile t-1)
            SSTORE(buf ^ 1);
            __syncthreads();      // stores visible before compute(t+1)
        }
    }

    if (m == 0) {
        const float bqc = bq[c];
        #pragma unroll
        for (int r = 0; r < 8; ++r)
            ws[EAOFF + (size_t)(rw + r) * DD + c] =
                EXP2F(TWO_LOG2E * (acc[r] + bqc));
    } else if (m == 1) {
        #pragma unroll
        for (int r = 0; r < 8; ++r) {
            const int row = rw + r;
            const int bi  = (row >= SS) ? 1 : 0;
            const int sl  = row - bi * SS;
            ws[EB4OFF + (size_t)((bi * 128 + (c >> 2)) * SS + sl) * 4 + (c & 3)] =
                EXP2F(TWO_LOG2E * acc[r]);
        }
    } else if (m == 2) {
        #pragma unroll
        for (int r = 0; r < 8; ++r)
            ws[MOFF + (size_t)(rw + r) * DD + c] = acc[r];
    } else {
        const float boc = bout[c];
        #pragma unroll
        for (int r = 0; r < 8; ++r) {
            const int row = rw + r;
            const int bi  = (row >= SS) ? 1 : 0;
            const int tb  = row - bi * SS;
            out0[((size_t)(tb * BB + bi)) * DD + c] = acc[r] + boc;
        }
    }
}

// ---------------------------------------------------------------------------
// K2a: partial scores over an e-quarter, 4 t's per block.
// Grid (100 t-quads, 2 b, 4 eq) = 800 blocks, 448 thr; thread = s.
// partial(t,s) = -2 * sum_{e in q} v_e / (Ea[t][e]*Eb[e][s] + 1)
// (score = Sigma v - that; the t,s-independent Sigma v cancels in softmax)
// Eb: float4-packed coalesced; Ea/v: block-uniform scalar path.
// ---------------------------------------------------------------------------
__global__ __launch_bounds__(448) void k2a_score(
    const float* __restrict__ ws, const float* __restrict__ v,
    float* __restrict__ part)
{
    const int tq = blockIdx.x;            // 0..99
    const int b  = blockIdx.y;
    const int eq = blockIdx.z;            // 0..3
    const int t0 = tq * 4;
    const int s  = threadIdx.x;
    const int sidx = (s < SS) ? s : 0;
    const int e0 = eq * 128;

    const float4* __restrict__ eb4 =
        (const float4*)(ws + EB4OFF) + ((size_t)b * 128 + (e0 >> 2)) * SS + sidx;
    const float* __restrict__ ea0 = ws + EAOFF + ((size_t)(b * SS + t0)) * DD + e0;
    const float* __restrict__ ea1 = ea0 + DD;
    const float* __restrict__ ea2 = ea1 + DD;
    const float* __restrict__ ea3 = ea2 + DD;
    const float* __restrict__ vp  = v + e0;

    float acc0 = 0.f, acc1 = 0.f, acc2 = 0.f, acc3 = 0.f;
    #pragma unroll 8
    for (int e4 = 0; e4 < 32; ++e4) {
        const float4 eb = eb4[(size_t)e4 * SS];
        const int e = e4 * 4;
        #pragma unroll
        for (int j = 0; j < 4; ++j) {
            const float ebv = (&eb.x)[j];
            const float vv  = vp[e + j];
            acc0 = fmaf(vv, RCPF(fmaf(ea0[e + j], ebv, 1.f)), acc0);
            acc1 = fmaf(vv, RCPF(fmaf(ea1[e + j], ebv, 1.f)), acc1);
            acc2 = fmaf(vv, RCPF(fmaf(ea2[e + j], ebv, 1.f)), acc2);
            acc3 = fmaf(vv, RCPF(fmaf(ea3[e + j], ebv, 1.f)), acc3);
        }
    }

    if (s < SS) {
        float* __restrict__ pp = part + (size_t)eq * PARTCH
                               + ((size_t)(b * SS + t0)) * SS + s;
        pp[0 * SS]  = -2.f * acc0;
        pp[1 * SS]  = -2.f * acc1;
        pp[2 * SS]  = -2.f * acc2;
        pp[3 * SS]  = -2.f * acc3;
    }
}

// ---------------------------------------------------------------------------
// K2b: combine 4 partials, mask, softmax, write align [T,B,S]. Grid 800.
// ---------------------------------------------------------------------------
__global__ __launch_bounds__(448) void k2b_softmax(
    const float* __restrict__ part, const int* __restrict__ lens,
    float* __restrict__ align_out)
{
    const int bt = blockIdx.x;            // b*SS + t
    const int b  = bt / SS;
    const int t  = bt - b * SS;
    const int tid = threadIdx.x;
    const int s   = tid;
    const int len = lens[b];

    float sc = -INFINITY;
    bool valid = false;
    if (s < SS) {
        valid = (s < len) && (s != t);
        if (valid) {
            const size_t idx = (size_t)bt * SS + s;
            sc = (part[idx] + part[PARTCH + idx])
               + (part[2 * (size_t)PARTCH + idx] + part[3 * (size_t)PARTCH + idx]);
        }
    }

    __shared__ float wred[8];
    const int wid  = tid >> 6;
    const int lane = tid & 63;

    float m = sc;
    #pragma unroll
    for (int off = 32; off > 0; off >>= 1) m = fmaxf(m, __shfl_xor(m, off));
    if (lane == 0) wred[wid] = m;
    __syncthreads();
    float mx = wred[0];
    #pragma unroll
    for (int w = 1; w < 7; ++w) mx = fmaxf(mx, wred[w]);
    __syncthreads();

    const float p = valid ? __expf(sc - mx) : 0.f;
    float sm = p;
    #pragma unroll
    for (int off = 32; off > 0; off >>= 1) sm += __shfl_xor(sm, off);
    if (lane == 0) wred[wid] = sm;
    __syncthreads();
    float tot = wred[0];
    #pragma unroll
    for (int w = 1; w < 7; ++w) tot += wred[w];
    const float inv = RCPF(tot);

    if (s < SS) align_out[((size_t)(t * BB) + b) * SS + s] = p * inv;
}

// ---------------------------------------------------------------------------
// K3: out0[t,b,d] += sum_s align[t,b,s] * M[b,s,d]. Grid (2,200), 256 thr.
// Thread = 4 t-rows x 1 d col; full s per block (no atomics); 2-phase
// prefetch.
// ---------------------------------------------------------------------------
__global__ __launch_bounds__(256) void k3_out(
    const float* __restrict__ ws, const float* __restrict__ align_out,
    float* __restrict__ out0)
{
    const int d     = blockIdx.x * 256 + threadIdx.x;
    const int r0    = blockIdx.y * 4;
    const int b     = (r0 >= SS) ? 1 : 0;
    const int tbase = r0 - b * SS;

    const float* __restrict__ Mb = ws + MOFF + (size_t)b * SS * DD;

    float pv[4];
    #pragma unroll
    for (int j = 0; j < 4; ++j)
        pv[j] = out0[((size_t)((tbase + j) * BB) + b) * DD + d];

    float acc[4];
    #pragma unroll
    for (int j = 0; j < 4; ++j) acc[j] = 0.f;

    float mA[4], mB[4];
    float4 alA[4], alB[4];

    auto LOAD = [&](float (&mm)[4], float4 (&al)[4], int s) {
        #pragma unroll
        for (int i = 0; i < 4; ++i)
            mm[i] = Mb[(size_t)(s + i) * DD + d];
        #pragma unroll
        for (int j = 0; j < 4; ++j)
            al[j] = *(const float4*)(align_out +
                     ((size_t)((tbase + j) * BB) + b) * SS + s);
    };
    auto FMA4 = [&](const float (&mm)[4], const float4 (&al)[4]) {
        #pragma unroll
        for (int j = 0; j < 4; ++j) {
            acc[j] = fmaf(al[j].x, mm[0], acc[j]);
            acc[j] = fmaf(al[j].y, mm[1], acc[j]);
            acc[j] = fmaf(al[j].z, mm[2], acc[j]);
            acc[j] = fmaf(al[j].w, mm[3], acc[j]);
        }
    };

    LOAD(mA, alA, 0);
    for (int s = 0; s < SS; s += 8) {
        LOAD(mB, alB, s + 4);
        FMA4(mA, alA);
        if (s + 8 < SS) LOAD(mA, alA, s + 8);
        FMA4(mB, alB);
    }

    #pragma unroll
    for (int j = 0; j < 4; ++j)
        out0[((size_t)((tbase + j) * BB) + b) * DD + d] = acc[j] + pv[j];
}

// ---------------------------------------------------------------------------
extern "C" void kernel_launch(void* const* d_in, const int* in_sizes, int n_in,
                              void* d_out, int out_size, void* d_ws, size_t ws_size,
                              hipStream_t stream)
{
    const float* input = (const float*)d_in[0];
    const float* mb    = (const float*)d_in[1];
    const int*   lens  = (const int*)d_in[2];
    const float* Wq    = (const float*)d_in[3];
    const float* bq    = (const float*)d_in[4];
    const float* Wc    = (const float*)d_in[5];
    const float* v     = (const float*)d_in[6];
    const float* Wout  = (const float*)d_in[7];
    const float* bout  = (const float*)d_in[8];

    float* out0 = (float*)d_out;               // [T,B,D] = 409600
    float* out1 = out0 + (size_t)BB * SS * DD; // [T,B,S] = 320000
    float* ws   = (float*)d_ws;

    hipLaunchKernelGGL(k1_gemm, dim3(25, 8, 4), dim3(256), 0, stream,
                       input, mb, Wq, bq, Wc, Wout, bout, ws, out0);
    hipLaunchKernelGGL(k2a_score, dim3(100, 2, 4), dim3(448), 0, stream,
                       ws, v, ws + PARTOFF);
    hipLaunchKernelGGL(k2b_softmax, dim3(800), dim3(448), 0, stream,
                       ws + PARTOFF, lens, out1);
    hipLaunchKernelGGL(k3_out, dim3(2, 200), dim3(256), 0, stream,
                       ws, out1, out0);
}

// Round 9
// 155.416 us; speedup vs baseline: 1.3744x; 1.3744x over previous
//
#include <hip/hip_runtime.h>
#include <math.h>

// Problem constants (reference: B=2, S=T=400, D=512)
#define BB 2
#define SS 400
#define DD 512
#define TWO_LOG2E 2.8853900817779268f

#if __has_builtin(__builtin_amdgcn_exp2f)
#define EXP2F(x) __builtin_amdgcn_exp2f(x)
#else
#define EXP2F(x) exp2f(x)
#endif
#define RCPF(x) __builtin_amdgcn_rcpf(x)

// Workspace float layout (peak 2,188,800 floats = 8.76 MB; 10.04 MB proven safe):
//   Ea   [0,       409600) : exp2(2L*(input@Wq + bq))            [B,T,D]
//   M    [409600,  819200) : mb@Wout_top                         [B,S,D]
//   Eb4  [819200, 1228800) : exp2(2L*(mb@Wc)), packed [B][D/4][S][4]
//   X    [1228800, ...)    : phase 1 (k0/k1): Wt bf16 [g][1024][512] (2.1 MB)
//                            phase 2 (k2a/k2b): part chunks 1..3 (3x320000 f)
//   (score partial chunk 0 lives in out1 in [t,b,s] layout; k2b overwrites it)
#define EAOFF 0
#define MOFF 409600
#define EB4OFF 819200
#define XOFF 1228800
#define PARTCH 320000

typedef __bf16 bf16x8 __attribute__((ext_vector_type(8)));
typedef float floatx16 __attribute__((ext_vector_type(16)));

// ---------------------------------------------------------------------------
// K0: build Wt[g][n][k] (bf16, k-contiguous) from the fp32 weights.
//   g0: n<512 -> Wq[k][n]         ; n>=512 -> Wout[512+k][n-512]  (bot half)
//   g1: n<512 -> Wc[k][n]         ; n>=512 -> Wout[k][n-512]      (top half)
// 32x32 LDS transpose tiles; grid (16 ktiles, 32 ntiles, 2 g), 256 thr.
// ---------------------------------------------------------------------------
__global__ __launch_bounds__(256) void k0_prep(
    const float* __restrict__ Wq, const float* __restrict__ Wc,
    const float* __restrict__ Wout, unsigned short* __restrict__ wt)
{
    const int k0 = blockIdx.x * 32;
    const int n0 = blockIdx.y * 32;
    const int g  = blockIdx.z;

    __shared__ float tile[32][33];
    const int nn  = threadIdx.x & 31;
    const int kk0 = threadIdx.x >> 5;
    const int n   = n0 + nn;

    #pragma unroll
    for (int p = 0; p < 4; ++p) {
        const int k = k0 + kk0 + p * 8;
        float val;
        if (n0 < 512) val = (g ? Wc : Wq)[(size_t)k * 512 + n];
        else          val = Wout[((size_t)(g ? k : 512 + k)) * 512 + (n - 512)];
        tile[kk0 + p * 8][nn] = val;
    }
    __syncthreads();

    const int kc = threadIdx.x & 31;
    #pragma unroll
    for (int p = 0; p < 4; ++p) {
        const int nl = (threadIdx.x >> 5) + p * 8;
        const __bf16 h = (__bf16)tile[kc][nl];
        wt[((size_t)(g * 1024 + n0 + nl)) * 512 + k0 + kc] =
            __builtin_bit_cast(unsigned short, h);
    }
}

// ---------------------------------------------------------------------------
// K1: two merged GEMMs (800 x 1024 x 512) via MFMA bf16 two-term split.
// Grid (25 mtiles, 16 npairs, 2 g), 64 thr = 1 wave; wave tile 32x64.
// A fp32 loaded direct (full 64B-line use), split in-register a = ahi+alo;
// B = Wt bf16 (hi only). acc = ahi*B + alo*B in 4 independent MFMA chains.
// A-frag: lane holds A[m=lane&31][k=ks*16+(lane>>5)*8 + 0..7].
// B-frag: lane holds Wt[n=lane&31][same k range].
// C/D:    col=lane&31, row=(reg&3)+8*(reg>>2)+4*(lane>>5)  [m74/m101].
// Fused epilogues by n-range/g: Ea, out0(=P+bout), Eb4 scatter, M.
// ---------------------------------------------------------------------------
__global__ __launch_bounds__(64) void k1_mfma(
    const float* __restrict__ input, const float* __restrict__ mb,
    const unsigned short* __restrict__ wt, const float* __restrict__ bq,
    const float* __restrict__ bout, float* __restrict__ ws,
    float* __restrict__ out0)
{
    const int lane = threadIdx.x;
    const int mt   = blockIdx.x;          // 0..24
    const int np   = blockIdx.y;          // 0..15
    const int g    = blockIdx.z;
    const int m    = lane & 31;
    const int kh   = lane >> 5;
    const int n0   = np * 64;

    const float* __restrict__ A = g ? mb : input;
    const float* __restrict__ Arow = A + (size_t)(mt * 32 + m) * 512;
    const unsigned short* __restrict__ w0 =
        wt + ((size_t)(g * 1024 + n0 + m)) * 512 + kh * 8;
    const unsigned short* __restrict__ w1 = w0 + (size_t)32 * 512;

    floatx16 acc0h, acc0l, acc1h, acc1l;
    #pragma unroll
    for (int i = 0; i < 16; ++i) { acc0h[i] = 0.f; acc0l[i] = 0.f;
                                   acc1h[i] = 0.f; acc1l[i] = 0.f; }

    #pragma unroll 4
    for (int ks = 0; ks < 32; ++ks) {
        const int kb = ks * 16 + kh * 8;
        const float4 a0 = *(const float4*)(Arow + kb);
        const float4 a1 = *(const float4*)(Arow + kb + 4);
        const bf16x8 bh0 = *(const bf16x8*)(w0 + ks * 16);
        const bf16x8 bh1 = *(const bf16x8*)(w1 + ks * 16);

        bf16x8 ah, al;
        const float av[8] = {a0.x, a0.y, a0.z, a0.w, a1.x, a1.y, a1.z, a1.w};
        #pragma unroll
        for (int i = 0; i < 8; ++i) {
            const __bf16 h = (__bf16)av[i];
            ah[i] = h;
            al[i] = (__bf16)(av[i] - (float)h);
        }

        acc0h = __builtin_amdgcn_mfma_f32_32x32x16_bf16(ah, bh0, acc0h, 0, 0, 0);
        acc0l = __builtin_amdgcn_mfma_f32_32x32x16_bf16(al, bh0, acc0l, 0, 0, 0);
        acc1h = __builtin_amdgcn_mfma_f32_32x32x16_bf16(ah, bh1, acc1h, 0, 0, 0);
        acc1l = __builtin_amdgcn_mfma_f32_32x32x16_bf16(al, bh1, acc1l, 0, 0, 0);
    }

    const floatx16 c0 = acc0h + acc0l;
    const floatx16 c1 = acc1h + acc1l;
    const int rbase = kh * 4;

    #pragma unroll
    for (int r = 0; r < 16; ++r) {
        const int row  = (r & 3) + 8 * (r >> 2) + rbase;   // 0..31
        const int grow = mt * 32 + row;                    // 0..799
        const int bi   = (grow >= SS) ? 1 : 0;
        const int rl   = grow - bi * SS;                   // t or s local
        #pragma unroll
        for (int u = 0; u < 2; ++u) {
            const float val  = u ? c1[r] : c0[r];
            const int   gcol = n0 + u * 32 + m;
            if (g == 0) {
                if (gcol < 512) {
                    ws[EAOFF + (size_t)grow * 512 + gcol] =
                        EXP2F(TWO_LOG2E * (val + bq[gcol]));
                } else {
                    const int d = gcol - 512;
                    out0[((size_t)(rl * BB + bi)) * 512 + d] = val + bout[d];
                }
            } else {
                if (gcol < 512) {
                    ws[EB4OFF + (size_t)((bi * 128 + (gcol >> 2)) * SS + rl) * 4
                       + (gcol & 3)] = EXP2F(TWO_LOG2E * val);
                } else {
                    ws[MOFF + (size_t)grow * 512 + (gcol - 512)] = val;
                }
            }
        }
    }
}

// ---------------------------------------------------------------------------
// K2a: partial scores over an e-quarter, 4 t's per block, Ea/v staged in LDS.
// Grid (100 tq, 2 b, 4 eq) = 800 blocks, 448 thr; thread = s.
// partial(t,s) = -2 * sum_e v_e / (Ea[t][e]*Eb[e][s] + 1)
// eq==0 writes into out1 ([t,b,s]); eq>0 into ws part chunk eq-1 ([b,t,s]).
// ---------------------------------------------------------------------------
__global__ __launch_bounds__(448) void k2a_score(
    const float* __restrict__ ws, const float* __restrict__ v,
    float* __restrict__ part, float* __restrict__ out1)
{
    const int tq = blockIdx.x;
    const int b  = blockIdx.y;
    const int eq = blockIdx.z;
    const int t0 = tq * 4;
    const int s  = threadIdx.x;
    const int sidx = (s < SS) ? s : 0;

    __shared__ float lea[4][128];
    __shared__ float lv[128];
    for (int i = threadIdx.x; i < 512; i += 448)
        lea[i >> 7][i & 127] =
            ws[EAOFF + (size_t)(b * SS + t0 + (i >> 7)) * 512 + eq * 128 + (i & 127)];
    if (threadIdx.x < 128) lv[threadIdx.x] = v[eq * 128 + threadIdx.x];
    __syncthreads();

    const float4* __restrict__ eb4 =
        (const float4*)(ws + EB4OFF) + ((size_t)b * 128 + eq * 32) * SS + sidx;

    float acc[4] = {0.f, 0.f, 0.f, 0.f};
    #pragma unroll 4
    for (int e4 = 0; e4 < 32; ++e4) {
        const float4 eb  = eb4[(size_t)e4 * SS];
        const float4 vv  = *(const float4*)&lv[e4 * 4];
        const float4 ea0 = *(const float4*)&lea[0][e4 * 4];
        const float4 ea1 = *(const float4*)&lea[1][e4 * 4];
        const float4 ea2 = *(const float4*)&lea[2][e4 * 4];
        const float4 ea3 = *(const float4*)&lea[3][e4 * 4];
        #pragma unroll
        for (int j = 0; j < 4; ++j) {
            const float ebv = (&eb.x)[j];
            const float vj  = (&vv.x)[j];
            acc[0] = fmaf(vj, RCPF(fmaf((&ea0.x)[j], ebv, 1.f)), acc[0]);
            acc[1] = fmaf(vj, RCPF(fmaf((&ea1.x)[j], ebv, 1.f)), acc[1]);
            acc[2] = fmaf(vj, RCPF(fmaf((&ea2.x)[j], ebv, 1.f)), acc[2]);
            acc[3] = fmaf(vj, RCPF(fmaf((&ea3.x)[j], ebv, 1.f)), acc[3]);
        }
    }

    if (s < SS) {
        if (eq == 0) {
            #pragma unroll
            for (int t = 0; t < 4; ++t)
                out1[((size_t)((t0 + t) * BB) + b) * SS + s] = -2.f * acc[t];
        } else {
            float* __restrict__ pp = part + (size_t)(eq - 1) * PARTCH
                                   + ((size_t)(b * SS + t0)) * SS + s;
            #pragma unroll
            for (int t = 0; t < 4; ++t)
                pp[(size_t)t * SS] = -2.f * acc[t];
        }
    }
}

// ---------------------------------------------------------------------------
// K2b: combine 4 partials (chunk0 in out1), mask, softmax, overwrite out1
// with align [T,B,S]. Grid 800, 448 thr. Per-thread read/write same addr.
// ---------------------------------------------------------------------------
__global__ __launch_bounds__(448) void k2b_softmax(
    const float* __restrict__ part, const int* __restrict__ lens,
    float* __restrict__ out1)
{
    const int bt = blockIdx.x;
    const int b  = bt / SS;
    const int t  = bt - b * SS;
    const int tid = threadIdx.x;
    const int s   = tid;
    const int len = lens[b];

    float sc = -INFINITY;
    bool valid = false;
    if (s < SS) {
        valid = (s < len) && (s != t);
        if (valid) {
            const size_t ibts = ((size_t)(t * BB) + b) * SS + s;
            const size_t idx  = (size_t)bt * SS + s;
            sc = out1[ibts] + part[idx]
               + part[PARTCH + idx] + part[2 * (size_t)PARTCH + idx];
        }
    }

    __shared__ float wred[8];
    const int wid  = tid >> 6;
    const int lane = tid & 63;

    float m = sc;
    #pragma unroll
    for (int off = 32; off > 0; off >>= 1) m = fmaxf(m, __shfl_xor(m, off));
    if (lane == 0) wred[wid] = m;
    __syncthreads();
    float mx = wred[0];
    #pragma unroll
    for (int w = 1; w < 7; ++w) mx = fmaxf(mx, wred[w]);
    __syncthreads();

    const float p = valid ? __expf(sc - mx) : 0.f;
    float sm = p;
    #pragma unroll
    for (int off = 32; off > 0; off >>= 1) sm += __shfl_xor(sm, off);
    if (lane == 0) wred[wid] = sm;
    __syncthreads();
    float tot = wred[0];
    #pragma unroll
    for (int w = 1; w < 7; ++w) tot += wred[w];
    const float inv = RCPF(tot);

    if (s < SS) out1[((size_t)(t * BB) + b) * SS + s] = p * inv;
}

// ---------------------------------------------------------------------------
// K3: out0[t,b,d] += sum_s align[t,b,s] * M[b,s,d]. Grid (2,200), 256 thr.
// Thread = 4 t-rows x 1 d col; 2-phase prefetch; no atomics.
// ---------------------------------------------------------------------------
__global__ __launch_bounds__(256) void k3_out(
    const float* __restrict__ ws, const float* __restrict__ align_out,
    float* __restrict__ out0)
{
    const int d     = blockIdx.x * 256 + threadIdx.x;
    const int r0    = blockIdx.y * 4;
    const int b     = (r0 >= SS) ? 1 : 0;
    const int tbase = r0 - b * SS;

    const float* __restrict__ Mb = ws + MOFF + (size_t)b * SS * DD;

    float pv[4];
    #pragma unroll
    for (int j = 0; j < 4; ++j)
        pv[j] = out0[((size_t)((tbase + j) * BB) + b) * DD + d];

    float acc[4];
    #pragma unroll
    for (int j = 0; j < 4; ++j) acc[j] = 0.f;

    float mA[4], mB[4];
    float4 alA[4], alB[4];

    auto LOAD = [&](float (&mm)[4], float4 (&al)[4], int s) {
        #pragma unroll
        for (int i = 0; i < 4; ++i)
            mm[i] = Mb[(size_t)(s + i) * DD + d];
        #pragma unroll
        for (int j = 0; j < 4; ++j)
            al[j] = *(const float4*)(align_out +
                     ((size_t)((tbase + j) * BB) + b) * SS + s);
    };
    auto FMA4 = [&](const float (&mm)[4], const float4 (&al)[4]) {
        #pragma unroll
        for (int j = 0; j < 4; ++j) {
            acc[j] = fmaf(al[j].x, mm[0], acc[j]);
            acc[j] = fmaf(al[j].y, mm[1], acc[j]);
            acc[j] = fmaf(al[j].z, mm[2], acc[j]);
            acc[j] = fmaf(al[j].w, mm[3], acc[j]);
        }
    };

    LOAD(mA, alA, 0);
    for (int s = 0; s < SS; s += 8) {
        LOAD(mB, alB, s + 4);
        FMA4(mA, alA);
        if (s + 8 < SS) LOAD(mA, alA, s + 8);
        FMA4(mB, alB);
    }

    #pragma unroll
    for (int j = 0; j < 4; ++j)
        out0[((size_t)((tbase + j) * BB) + b) * DD + d] = acc[j] + pv[j];
}

// ---------------------------------------------------------------------------
extern "C" void kernel_launch(void* const* d_in, const int* in_sizes, int n_in,
                              void* d_out, int out_size, void* d_ws, size_t ws_size,
                              hipStream_t stream)
{
    const float* input = (const float*)d_in[0];
    const float* mb    = (const float*)d_in[1];
    const int*   lens  = (const int*)d_in[2];
    const float* Wq    = (const float*)d_in[3];
    const float* bq    = (const float*)d_in[4];
    const float* Wc    = (const float*)d_in[5];
    const float* v     = (const float*)d_in[6];
    const float* Wout  = (const float*)d_in[7];
    const float* bout  = (const float*)d_in[8];

    float* out0 = (float*)d_out;               // [T,B,D] = 409600
    float* out1 = out0 + (size_t)BB * SS * DD; // [T,B,S] = 320000
    float* ws   = (float*)d_ws;
    unsigned short* wt = (unsigned short*)(ws + XOFF);
    float* part = ws + XOFF;                   // phase 2 alias over wt

    hipLaunchKernelGGL(k0_prep, dim3(16, 32, 2), dim3(256), 0, stream,
                       Wq, Wc, Wout, wt);
    hipLaunchKernelGGL(k1_mfma, dim3(25, 16, 2), dim3(64), 0, stream,
                       input, mb, wt, bq, bout, ws, out0);
    hipLaunchKernelGGL(k2a_score, dim3(100, 2, 4), dim3(448), 0, stream,
                       ws, v, part, out1);
    hipLaunchKernelGGL(k2b_softmax, dim3(800), dim3(448), 0, stream,
                       part, lens, out1);
    hipLaunchKernelGGL(k3_out, dim3(2, 200), dim3(256), 0, stream,
                       ws, out1, out0);
}